// Round 8
// baseline (3875.788 us; speedup 1.0000x reference)
//
#include <hip/hip_runtime.h>

#define NCP    64
#define BTS    16
#define NTPL   2048
#define TSTEPS 6
#define DTF    0.2f                      // 1/(T-1)
#define L2E    1.4426950408889634f       // log2(e)
#define NW     193                       // transformed-weight count

typedef float v2f __attribute__((ext_vector_type(2)));

// ---------- fast scalar helpers ----------
__device__ __forceinline__ float fast_rcp(float x) { return __builtin_amdgcn_rcpf(x); }
__device__ __forceinline__ float fexp2(float x)    { return __builtin_amdgcn_exp2f(x); }
__device__ __forceinline__ float fast_tanh(float x) {        // shoot path
    float e = __expf(2.0f * x);
    return 1.0f - 2.0f * fast_rcp(1.0f + e);
}
__device__ __forceinline__ v2f fma2(v2f a, v2f b, v2f c) {
    return __builtin_elementwise_fma(a, b, c);
}
__device__ __forceinline__ v2f splat(float s) { v2f v; v.x = s; v.y = s; return v; }

// ======================================================================
// Symmetrized 2x2 kernel block, transformed sigmoid weights, read from
// LDS (w points at a __shared__ staging buffer; kblock is force-inlined
// into the kernels so addrspace inference emits ds_read broadcasts).
// w layout: W1t[40] b1t[10] W2t[100] b2t[10] C0[10] C1[10] C2[10] b3t[3]
// (tanh folded as 1-2r, r=sigmoid; exp2 scales folded; 0.5 sym folded)
// ======================================================================
__device__ __forceinline__ void kblock(
    float x0, float x1, float p0, float p1,
    const float* w,
    float& M00, float& M01, float& M11)
{
    v2f z0, z1, z2, z3;
    z0.x = x0; z0.y = p0;
    z1.x = x1; z1.y = p1;
    z2.x = p0; z2.y = x0;
    z3.x = p1; z3.y = x1;

    v2f r[10];
#pragma unroll
    for (int k = 0; k < 10; ++k) {
        v2f t = fma2(z3, splat(w[30 + k]),
                fma2(z2, splat(w[20 + k]),
                fma2(z1, splat(w[10 + k]),
                fma2(z0, splat(w[k]), splat(w[40 + k])))));
        r[k].x = fast_rcp(1.0f + fexp2(t.x));
        r[k].y = fast_rcp(1.0f + fexp2(t.y));
    }
    v2f u[10];
#pragma unroll
    for (int k = 0; k < 10; ++k) u[k] = fma2(r[0], splat(w[50 + k]), splat(w[150 + k]));
#pragma unroll
    for (int c = 1; c < 10; ++c) {
#pragma unroll
        for (int k = 0; k < 10; ++k) u[k] = fma2(r[c], splat(w[50 + c * 10 + k]), u[k]);
    }
    v2f O  = splat(w[190]);
    v2f T1 = splat(w[191]);
    v2f T2 = splat(w[192]);
#pragma unroll
    for (int c = 0; c < 10; ++c) {
        v2f r2;
        r2.x = fast_rcp(1.0f + fexp2(u[c].x));
        r2.y = fast_rcp(1.0f + fexp2(u[c].y));
        O  = fma2(r2, splat(w[160 + c]), O);
        T1 = fma2(r2, splat(w[170 + c]), T1);
        T2 = fma2(r2, splat(w[180 + c]), T2);
    }
    M00 = fexp2(T1.x) + fexp2(T1.y);   // 0.5*(exp(o1a)+exp(o1b))
    M01 = O.x + O.y;
    M11 = fexp2(T2.x) + fexp2(T2.y);
}

// ======================================================================
// One symplectic shooting step (R2/R6-proven). Grid 1024(+1 on first).
// first!=0: read p from cp / q from q0; block 1024 folds wt instead.
// ======================================================================
__global__ __launch_bounds__(64, 1)
void shoot_step(const float* __restrict__ q0, const float* __restrict__ cp,
                const float* __restrict__ p_in, const float* __restrict__ q_in,
                float* __restrict__ p_out, float* __restrict__ q_out,
                const float* __restrict__ W1, const float* __restrict__ b1,
                const float* __restrict__ W2, const float* __restrict__ b2,
                const float* __restrict__ W3, const float* __restrict__ b3,
                float* __restrict__ wt, int first)
{
    int blk = blockIdx.x;
    if (first && blk == BTS * NCP) {
        // ---- weight transform for the flow kernels ----
        int t = threadIdx.x;
        if (t < 40) wt[t] = 2.0f * L2E * W1[t];
        if (t < 10) wt[40 + t] = 2.0f * L2E * b1[t];
        for (int i = t; i < 100; i += 64) wt[50 + i] = -4.0f * L2E * W2[i];
        if (t < 10) {
            float s = b2[t];
            for (int c = 0; c < 10; ++c) s += W2[c * 10 + t];
            wt[150 + t] = 2.0f * L2E * s;                 // b2''
            wt[160 + t] = -W3[t * 3 + 0];                 // C0 (0.5 * -2)
            wt[170 + t] = -2.0f * L2E * W3[t * 3 + 1];    // C1
            wt[180 + t] = -2.0f * L2E * W3[t * 3 + 2];    // C2
        }
        if (t < 3) {
            float s = b3[t];
            for (int c = 0; c < 10; ++c) s += W3[c * 3 + t];
            wt[190 + t] = (t == 0) ? 0.5f * s : fmaf(L2E, s, -1.0f);
        }
        return;
    }

    int batch = blk >> 6;
    int a = blk & (NCP - 1);
    int b = threadIdx.x;

    float pax, pay, qax, qay, pbx, pby, qbx, qby;
    if (first) {
        pax = cp[2 * a]; pay = cp[2 * a + 1];
        pbx = cp[2 * b]; pby = cp[2 * b + 1];
        qax = q0[(batch * NCP + a) * 2 + 0]; qay = q0[(batch * NCP + a) * 2 + 1];
        qbx = q0[(batch * NCP + b) * 2 + 0]; qby = q0[(batch * NCP + b) * 2 + 1];
    } else {
        const float* pB = p_in + batch * NCP * 2;
        const float* qB = q_in + batch * NCP * 2;
        pax = pB[a * 2 + 0]; pay = pB[a * 2 + 1];
        qax = qB[a * 2 + 0]; qay = qB[a * 2 + 1];
        pbx = pB[b * 2 + 0]; pby = pB[b * 2 + 1];
        qbx = qB[b * 2 + 0]; qby = qB[b * 2 + 1];
    }

    float dhq_x = 0.f, dhq_y = 0.f;
    float g_x = 0.f, g_y = 0.f;
    float cross = fmaf(qax, qby, qay * qbx);

#pragma unroll
    for (int e = 0; e < 2; ++e) {
        float z0 = e ? pbx : pax;
        float z1 = e ? pby : pay;
        float z2 = e ? pax : pbx;
        float z3 = e ? pay : pby;

        float h1[10];
#pragma unroll
        for (int k = 0; k < 10; ++k) {
            float u = fmaf(z3, W1[30 + k],
                      fmaf(z2, W1[20 + k],
                      fmaf(z1, W1[10 + k],
                      fmaf(z0, W1[k], b1[k]))));
            h1[k] = fast_tanh(u);
        }
        float u2[10];
#pragma unroll
        for (int k = 0; k < 10; ++k) u2[k] = b2[k];
#pragma unroll
        for (int c = 0; c < 10; ++c) {
#pragma unroll
            for (int k = 0; k < 10; ++k) u2[k] = fmaf(h1[c], W2[c * 10 + k], u2[k]);
        }
        float h2[10];
        float o0 = b3[0], o1 = b3[1], o2 = b3[2];
#pragma unroll
        for (int c = 0; c < 10; ++c) {
            h2[c] = fast_tanh(u2[c]);
            o0 = fmaf(h2[c], W3[c * 3 + 0], o0);
            o1 = fmaf(h2[c], W3[c * 3 + 1], o1);
            o2 = fmaf(h2[c], W3[c * 3 + 2], o2);
        }
        float e1 = __expf(o1), e2 = __expf(o2);

        dhq_x = fmaf(0.5f, fmaf(e1, qbx, o0 * qby), dhq_x);
        dhq_y = fmaf(0.5f, fmaf(o0, qbx, e2 * qby), dhq_y);

        float d0 = cross;
        float d1 = e1 * qax * qbx;
        float d2 = e2 * qay * qby;

        float du2[10];
#pragma unroll
        for (int c = 0; c < 10; ++c) {
            float dh2 = fmaf(W3[c * 3 + 0], d0,
                        fmaf(W3[c * 3 + 1], d1, W3[c * 3 + 2] * d2));
            du2[c] = dh2 * (1.0f - h2[c] * h2[c]);
        }
        float du1[10];
#pragma unroll
        for (int c = 0; c < 10; ++c) {
            float dh1 = 0.f;
#pragma unroll
            for (int k = 0; k < 10; ++k) dh1 = fmaf(W2[c * 10 + k], du2[k], dh1);
            du1[c] = dh1 * (1.0f - h1[c] * h1[c]);
        }
        int c0 = e ? 2 : 0;
        float ga = 0.f, gb = 0.f;
#pragma unroll
        for (int k = 0; k < 10; ++k) {
            ga = fmaf(W1[(0 + c0) * 10 + k], du1[k], ga);
            gb = fmaf(W1[(1 + c0) * 10 + k], du1[k], gb);
        }
        g_x = fmaf(0.5f, ga, g_x);
        g_y = fmaf(0.5f, gb, g_y);
    }

#pragma unroll
    for (int off = 32; off > 0; off >>= 1) {
        dhq_x += __shfl_xor(dhq_x, off);
        dhq_y += __shfl_xor(dhq_y, off);
        g_x   += __shfl_xor(g_x, off);
        g_y   += __shfl_xor(g_y, off);
    }

    if (b == 0) {
        float* pO = p_out + (batch * NCP + a) * 2;
        float* qO = q_out + (batch * NCP + a) * 2;
        pO[0] = fmaf(DTF, dhq_x, pax);
        pO[1] = fmaf(DTF, dhq_y, pay);
        qO[0] = fmaf(-DTF, g_x, qax);
        qO[1] = fmaf(-DTF, g_y, qay);
    }
}

// ======================================================================
// Flow step 0: x == tpl, p == cp for ALL batches -> one kblock per (i,j),
// apply all 16 batches' q. Writes x^(1) into d_out.
// ======================================================================
__global__ __launch_bounds__(256, 4)
void flow_step0(const float* __restrict__ tpl, const float* __restrict__ cp,
                const float* __restrict__ q0, float* __restrict__ out,
                const float* __restrict__ wt)
{
    __shared__ float w[NW];
    for (int t = threadIdx.x; t < NW; t += 256) w[t] = wt[t];
    __syncthreads();

    int i = blockIdx.x * 4 + (threadIdx.x >> 6);
    int j = threadIdx.x & 63;

    float x0 = tpl[2 * i], x1 = tpl[2 * i + 1];
    float p0 = cp[2 * j],  p1 = cp[2 * j + 1];

    float M00, M01, M11;
    kblock(x0, x1, p0, p1, w, M00, M01, M11);

    const float2* __restrict__ q = (const float2*)q0;
#pragma unroll
    for (int bt = 0; bt < BTS; ++bt) {
        float2 qq = q[bt * NCP + j];
        float vx = fmaf(M00, qq.x, M01 * qq.y);
        float vy = fmaf(M01, qq.x, M11 * qq.y);
#pragma unroll
        for (int off = 32; off > 0; off >>= 1) {
            vx += __shfl_xor(vx, off);
            vy += __shfl_xor(vy, off);
        }
        if (j == 0) {
            out[((size_t)bt * NTPL + i) * 2 + 0] = fmaf(DTF, vx, x0);
            out[((size_t)bt * NTPL + i) * 2 + 1] = fmaf(DTF, vy, x1);
        }
    }
}

// ======================================================================
// Flow steps 1..6: wave = (batch, i), lane = control point j.
// Small body (unroll 1) + 1-step software pipeline on the P/Q loads
// (they don't depend on x, so next step's loads hide under kblock).
// ======================================================================
__global__ __launch_bounds__(256, 4)
void flow_rest(const float* __restrict__ p_hist, const float* __restrict__ q_hist,
               float* __restrict__ out, const float* __restrict__ wt)
{
    __shared__ float w[NW];
    for (int t = threadIdx.x; t < NW; t += 256) w[t] = wt[t];
    __syncthreads();

    int unit = blockIdx.x * 4 + (threadIdx.x >> 6);
    int j = threadIdx.x & 63;
    int batch = unit >> 11;
    int i = unit & (NTPL - 1);

    const float2* __restrict__ ph = (const float2*)p_hist;
    const float2* __restrict__ qh = (const float2*)q_hist;

    size_t oidx = ((size_t)batch * NTPL + i) * 2;
    float x0 = out[oidx + 0];
    float x1 = out[oidx + 1];

    int base = BTS * NCP + batch * NCP + j;     // slab 1 index
    float2 Pc = ph[base];
    float2 Qc = qh[base];

#pragma unroll 1
    for (int s = 0; s < TSTEPS; ++s) {
        float2 Pn, Qn;
        if (s < TSTEPS - 1) {
            int idx = base + (s + 1) * BTS * NCP;
            Pn = ph[idx];
            Qn = qh[idx];
        }
        float M00, M01, M11;
        kblock(x0, x1, Pc.x, Pc.y, w, M00, M01, M11);
        float vx = fmaf(M00, Qc.x, M01 * Qc.y);
        float vy = fmaf(M01, Qc.x, M11 * Qc.y);
#pragma unroll
        for (int off = 32; off > 0; off >>= 1) {
            vx += __shfl_xor(vx, off);
            vy += __shfl_xor(vy, off);
        }
        x0 = fmaf(DTF, vx, x0);
        x1 = fmaf(DTF, vy, x1);
        Pc = Pn;
        Qc = Qn;
    }

    if (j == 0) {
        out[oidx + 0] = x0;
        out[oidx + 1] = x1;
    }
}

extern "C" void kernel_launch(void* const* d_in, const int* in_sizes, int n_in,
                              void* d_out, int out_size, void* d_ws, size_t ws_size,
                              hipStream_t stream)
{
    const float* q0  = (const float*)d_in[0];   // [16,64,2]
    const float* tpl = (const float*)d_in[1];   // [2048,2]
    const float* cp  = (const float*)d_in[2];   // [64,2]
    const float* W1  = (const float*)d_in[3];   // [4,10]
    const float* b1  = (const float*)d_in[4];   // [10]
    const float* W2  = (const float*)d_in[5];   // [10,10]
    const float* b2  = (const float*)d_in[6];   // [10]
    const float* W3  = (const float*)d_in[7];   // [10,3]
    const float* b3  = (const float*)d_in[8];   // [3]
    float* out = (float*)d_out;

    float* ws = (float*)d_ws;
    const int slab = BTS * NCP * 2;                      // 2048 floats / slice
    float* p_hist = ws;                                  // 7 slabs (slot 0 unused)
    float* q_hist = ws + (size_t)7 * slab;
    float* wt     = ws + (size_t)14 * slab;              // 193 floats

    shoot_step<<<BTS * NCP + 1, 64, 0, stream>>>(
        q0, cp, nullptr, nullptr,
        p_hist + (size_t)1 * slab, q_hist + (size_t)1 * slab,
        W1, b1, W2, b2, W3, b3, wt, 1);
    for (int s = 1; s < TSTEPS; ++s) {
        shoot_step<<<BTS * NCP, 64, 0, stream>>>(
            q0, cp,
            p_hist + (size_t)s * slab, q_hist + (size_t)s * slab,
            p_hist + (size_t)(s + 1) * slab, q_hist + (size_t)(s + 1) * slab,
            W1, b1, W2, b2, W3, b3, wt, 0);
    }

    flow_step0<<<NTPL / 4, 256, 0, stream>>>(tpl, cp, q0, out, wt);
    flow_rest<<<BTS * NTPL / 4, 256, 0, stream>>>(p_hist, q_hist, out, wt);
}

// Round 9
// 346.723 us; speedup vs baseline: 11.1783x; 11.1783x over previous
//
#include <hip/hip_runtime.h>

#define NCP    64
#define BTS    16
#define NTPL   2048
#define TSTEPS 6
#define DTF    0.2f                      // 1/(T-1)
#define L2E    1.4426950408889634f       // log2(e)

typedef float v2f __attribute__((ext_vector_type(2)));

// ---------- fast scalar helpers ----------
__device__ __forceinline__ float fast_rcp(float x) { return __builtin_amdgcn_rcpf(x); }
__device__ __forceinline__ float fexp2(float x)    { return __builtin_amdgcn_exp2f(x); }
__device__ __forceinline__ float fast_tanh(float x) {
    float e = __expf(2.0f * x);
    return 1.0f - 2.0f * fast_rcp(1.0f + e);
}
__device__ __forceinline__ v2f fma2(v2f a, v2f b, v2f c) {
    return __builtin_elementwise_fma(a, b, c);
}
__device__ __forceinline__ v2f splat(float s) { v2f v; v.x = s; v.y = s; return v; }

// ======================================================================
// Packed symmetrized 2x2 kernel block, transformed sigmoid weights
// (global memory, uniform __restrict__ -> s_load; R8 showed LDS staging
// causes scratch spills, R6 showed this path is correct at 277us).
// wt layout: W1t[40] b1t[10] W2t[100] b2t[10] C0[10] C1[10] C2[10] b3t[3]
// ======================================================================
__device__ __forceinline__ void kblock(
    float x0, float x1, float p0, float p1,
    const float* __restrict__ wt,
    float& M00, float& M01, float& M11)
{
    const float* __restrict__ W1t = wt;
    const float* __restrict__ b1t = wt + 40;
    const float* __restrict__ W2t = wt + 50;
    const float* __restrict__ b2t = wt + 150;
    const float* __restrict__ C0  = wt + 160;
    const float* __restrict__ C1  = wt + 170;
    const float* __restrict__ C2  = wt + 180;
    const float* __restrict__ b3t = wt + 190;

    v2f z0, z1, z2, z3;
    z0.x = x0; z0.y = p0;
    z1.x = x1; z1.y = p1;
    z2.x = p0; z2.y = x0;
    z3.x = p1; z3.y = x1;

    v2f r[10];
#pragma unroll
    for (int k = 0; k < 10; ++k) {
        v2f t = fma2(z3, splat(W1t[30 + k]),
                fma2(z2, splat(W1t[20 + k]),
                fma2(z1, splat(W1t[10 + k]),
                fma2(z0, splat(W1t[k]), splat(b1t[k])))));
        r[k].x = fast_rcp(1.0f + fexp2(t.x));
        r[k].y = fast_rcp(1.0f + fexp2(t.y));
    }
    v2f u[10];
#pragma unroll
    for (int k = 0; k < 10; ++k) u[k] = fma2(r[0], splat(W2t[k]), splat(b2t[k]));
#pragma unroll
    for (int c = 1; c < 10; ++c) {
#pragma unroll
        for (int k = 0; k < 10; ++k) u[k] = fma2(r[c], splat(W2t[c * 10 + k]), u[k]);
    }
    v2f O  = splat(b3t[0]);
    v2f T1 = splat(b3t[1]);
    v2f T2 = splat(b3t[2]);
#pragma unroll
    for (int c = 0; c < 10; ++c) {
        v2f r2;
        r2.x = fast_rcp(1.0f + fexp2(u[c].x));
        r2.y = fast_rcp(1.0f + fexp2(u[c].y));
        O  = fma2(r2, splat(C0[c]), O);
        T1 = fma2(r2, splat(C1[c]), T1);
        T2 = fma2(r2, splat(C2[c]), T2);
    }
    M00 = fexp2(T1.x) + fexp2(T1.y);
    M01 = O.x + O.y;
    M11 = fexp2(T2.x) + fexp2(T2.y);
}

// ======================================================================
// One symplectic shooting step (R2/R6-proven). Grid 1024(+1 on first).
// first!=0: read p from cp / q from q0; block 1024 folds wt instead.
// ======================================================================
__global__ __launch_bounds__(64, 1)
void shoot_step(const float* __restrict__ q0, const float* __restrict__ cp,
                const float* __restrict__ p_in, const float* __restrict__ q_in,
                float* __restrict__ p_out, float* __restrict__ q_out,
                const float* __restrict__ W1, const float* __restrict__ b1,
                const float* __restrict__ W2, const float* __restrict__ b2,
                const float* __restrict__ W3, const float* __restrict__ b3,
                float* __restrict__ wt, int first)
{
    int blk = blockIdx.x;
    if (first && blk == BTS * NCP) {
        int t = threadIdx.x;
        if (t < 40) wt[t] = 2.0f * L2E * W1[t];
        if (t < 10) wt[40 + t] = 2.0f * L2E * b1[t];
        for (int i = t; i < 100; i += 64) wt[50 + i] = -4.0f * L2E * W2[i];
        if (t < 10) {
            float s = b2[t];
            for (int c = 0; c < 10; ++c) s += W2[c * 10 + t];
            wt[150 + t] = 2.0f * L2E * s;                 // b2''
            wt[160 + t] = -W3[t * 3 + 0];                 // C0 (0.5 * -2)
            wt[170 + t] = -2.0f * L2E * W3[t * 3 + 1];    // C1
            wt[180 + t] = -2.0f * L2E * W3[t * 3 + 2];    // C2
        }
        if (t < 3) {
            float s = b3[t];
            for (int c = 0; c < 10; ++c) s += W3[c * 3 + t];
            wt[190 + t] = (t == 0) ? 0.5f * s : fmaf(L2E, s, -1.0f);
        }
        return;
    }

    int batch = blk >> 6;
    int a = blk & (NCP - 1);
    int b = threadIdx.x;

    float pax, pay, qax, qay, pbx, pby, qbx, qby;
    if (first) {
        pax = cp[2 * a]; pay = cp[2 * a + 1];
        pbx = cp[2 * b]; pby = cp[2 * b + 1];
        qax = q0[(batch * NCP + a) * 2 + 0]; qay = q0[(batch * NCP + a) * 2 + 1];
        qbx = q0[(batch * NCP + b) * 2 + 0]; qby = q0[(batch * NCP + b) * 2 + 1];
    } else {
        const float* pB = p_in + batch * NCP * 2;
        const float* qB = q_in + batch * NCP * 2;
        pax = pB[a * 2 + 0]; pay = pB[a * 2 + 1];
        qax = qB[a * 2 + 0]; qay = qB[a * 2 + 1];
        pbx = pB[b * 2 + 0]; pby = pB[b * 2 + 1];
        qbx = qB[b * 2 + 0]; qby = qB[b * 2 + 1];
    }

    float dhq_x = 0.f, dhq_y = 0.f;
    float g_x = 0.f, g_y = 0.f;
    float cross = fmaf(qax, qby, qay * qbx);

#pragma unroll
    for (int e = 0; e < 2; ++e) {
        float z0 = e ? pbx : pax;
        float z1 = e ? pby : pay;
        float z2 = e ? pax : pbx;
        float z3 = e ? pay : pby;

        float h1[10];
#pragma unroll
        for (int k = 0; k < 10; ++k) {
            float u = fmaf(z3, W1[30 + k],
                      fmaf(z2, W1[20 + k],
                      fmaf(z1, W1[10 + k],
                      fmaf(z0, W1[k], b1[k]))));
            h1[k] = fast_tanh(u);
        }
        float u2[10];
#pragma unroll
        for (int k = 0; k < 10; ++k) u2[k] = b2[k];
#pragma unroll
        for (int c = 0; c < 10; ++c) {
#pragma unroll
            for (int k = 0; k < 10; ++k) u2[k] = fmaf(h1[c], W2[c * 10 + k], u2[k]);
        }
        float h2[10];
        float o0 = b3[0], o1 = b3[1], o2 = b3[2];
#pragma unroll
        for (int c = 0; c < 10; ++c) {
            h2[c] = fast_tanh(u2[c]);
            o0 = fmaf(h2[c], W3[c * 3 + 0], o0);
            o1 = fmaf(h2[c], W3[c * 3 + 1], o1);
            o2 = fmaf(h2[c], W3[c * 3 + 2], o2);
        }
        float e1 = __expf(o1), e2 = __expf(o2);

        dhq_x = fmaf(0.5f, fmaf(e1, qbx, o0 * qby), dhq_x);
        dhq_y = fmaf(0.5f, fmaf(o0, qbx, e2 * qby), dhq_y);

        float d0 = cross;
        float d1 = e1 * qax * qbx;
        float d2 = e2 * qay * qby;

        float du2[10];
#pragma unroll
        for (int c = 0; c < 10; ++c) {
            float dh2 = fmaf(W3[c * 3 + 0], d0,
                        fmaf(W3[c * 3 + 1], d1, W3[c * 3 + 2] * d2));
            du2[c] = dh2 * (1.0f - h2[c] * h2[c]);
        }
        float du1[10];
#pragma unroll
        for (int c = 0; c < 10; ++c) {
            float dh1 = 0.f;
#pragma unroll
            for (int k = 0; k < 10; ++k) dh1 = fmaf(W2[c * 10 + k], du2[k], dh1);
            du1[c] = dh1 * (1.0f - h1[c] * h1[c]);
        }
        int c0 = e ? 2 : 0;
        float ga = 0.f, gb = 0.f;
#pragma unroll
        for (int k = 0; k < 10; ++k) {
            ga = fmaf(W1[(0 + c0) * 10 + k], du1[k], ga);
            gb = fmaf(W1[(1 + c0) * 10 + k], du1[k], gb);
        }
        g_x = fmaf(0.5f, ga, g_x);
        g_y = fmaf(0.5f, gb, g_y);
    }

#pragma unroll
    for (int off = 32; off > 0; off >>= 1) {
        dhq_x += __shfl_xor(dhq_x, off);
        dhq_y += __shfl_xor(dhq_y, off);
        g_x   += __shfl_xor(g_x, off);
        g_y   += __shfl_xor(g_y, off);
    }

    if (b == 0) {
        float* pO = p_out + (batch * NCP + a) * 2;
        float* qO = q_out + (batch * NCP + a) * 2;
        pO[0] = fmaf(DTF, dhq_x, pax);
        pO[1] = fmaf(DTF, dhq_y, pay);
        qO[0] = fmaf(-DTF, g_x, qax);
        qO[1] = fmaf(-DTF, g_y, qay);
    }
}

// ======================================================================
// Flow step 0: x == tpl, p == cp for ALL batches -> one kblock per (i,j),
// apply all 16 batches' q. Writes x^(1) into d_out.
// launch_bounds(256,2): VGPR cap 256 -> no remat churn (R9 experiment).
// ======================================================================
__global__ __launch_bounds__(256, 2)
void flow_step0(const float* __restrict__ tpl, const float* __restrict__ cp,
                const float* __restrict__ q0, float* __restrict__ out,
                const float* __restrict__ wt)
{
    int i = blockIdx.x * 4 + (threadIdx.x >> 6);
    int j = threadIdx.x & 63;

    float x0 = tpl[2 * i], x1 = tpl[2 * i + 1];
    float p0 = cp[2 * j],  p1 = cp[2 * j + 1];

    float M00, M01, M11;
    kblock(x0, x1, p0, p1, wt, M00, M01, M11);

    const float2* __restrict__ q = (const float2*)q0;
#pragma unroll
    for (int bt = 0; bt < BTS; ++bt) {
        float2 qq = q[bt * NCP + j];
        float vx = fmaf(M00, qq.x, M01 * qq.y);
        float vy = fmaf(M01, qq.x, M11 * qq.y);
#pragma unroll
        for (int off = 32; off > 0; off >>= 1) {
            vx += __shfl_xor(vx, off);
            vy += __shfl_xor(vy, off);
        }
        if (j == 0) {
            out[((size_t)bt * NTPL + i) * 2 + 0] = fmaf(DTF, vx, x0);
            out[((size_t)bt * NTPL + i) * 2 + 1] = fmaf(DTF, vy, x1);
        }
    }
}

// ======================================================================
// Flow steps 1..6: wave = (batch, i), lane = control point j.
// launch_bounds(256,2): VGPR cap 256 (was 64 at default 8 waves/EU) so
// the unrolled kblock doesn't rematerialize/reload under pressure.
// ======================================================================
__global__ __launch_bounds__(256, 2)
void flow_rest(const float* __restrict__ p_hist, const float* __restrict__ q_hist,
               float* __restrict__ out, const float* __restrict__ wt)
{
    int unit = blockIdx.x * 4 + (threadIdx.x >> 6);
    int j = threadIdx.x & 63;
    int batch = unit >> 11;
    int i = unit & (NTPL - 1);

    const float2* __restrict__ ph = (const float2*)p_hist;
    const float2* __restrict__ qh = (const float2*)q_hist;

    size_t oidx = ((size_t)batch * NTPL + i) * 2;
    float x0 = out[oidx + 0];
    float x1 = out[oidx + 1];

#pragma unroll
    for (int s = 0; s < TSTEPS; ++s) {
        int idx = ((s + 1) * BTS + batch) * NCP + j;
        float2 P = ph[idx];
        float2 Q = qh[idx];
        float M00, M01, M11;
        kblock(x0, x1, P.x, P.y, wt, M00, M01, M11);
        float vx = fmaf(M00, Q.x, M01 * Q.y);
        float vy = fmaf(M01, Q.x, M11 * Q.y);
#pragma unroll
        for (int off = 32; off > 0; off >>= 1) {
            vx += __shfl_xor(vx, off);
            vy += __shfl_xor(vy, off);
        }
        x0 = fmaf(DTF, vx, x0);
        x1 = fmaf(DTF, vy, x1);
    }

    if (j == 0) {
        out[oidx + 0] = x0;
        out[oidx + 1] = x1;
    }
}

extern "C" void kernel_launch(void* const* d_in, const int* in_sizes, int n_in,
                              void* d_out, int out_size, void* d_ws, size_t ws_size,
                              hipStream_t stream)
{
    const float* q0  = (const float*)d_in[0];   // [16,64,2]
    const float* tpl = (const float*)d_in[1];   // [2048,2]
    const float* cp  = (const float*)d_in[2];   // [64,2]
    const float* W1  = (const float*)d_in[3];   // [4,10]
    const float* b1  = (const float*)d_in[4];   // [10]
    const float* W2  = (const float*)d_in[5];   // [10,10]
    const float* b2  = (const float*)d_in[6];   // [10]
    const float* W3  = (const float*)d_in[7];   // [10,3]
    const float* b3  = (const float*)d_in[8];   // [3]
    float* out = (float*)d_out;

    float* ws = (float*)d_ws;
    const int slab = BTS * NCP * 2;                      // 2048 floats / slice
    float* p_hist = ws;                                  // 7 slabs (slot 0 unused)
    float* q_hist = ws + (size_t)7 * slab;
    float* wt     = ws + (size_t)14 * slab;              // 193 floats

    shoot_step<<<BTS * NCP + 1, 64, 0, stream>>>(
        q0, cp, nullptr, nullptr,
        p_hist + (size_t)1 * slab, q_hist + (size_t)1 * slab,
        W1, b1, W2, b2, W3, b3, wt, 1);
    for (int s = 1; s < TSTEPS; ++s) {
        shoot_step<<<BTS * NCP, 64, 0, stream>>>(
            q0, cp,
            p_hist + (size_t)s * slab, q_hist + (size_t)s * slab,
            p_hist + (size_t)(s + 1) * slab, q_hist + (size_t)(s + 1) * slab,
            W1, b1, W2, b2, W3, b3, wt, 0);
    }

    flow_step0<<<NTPL / 4, 256, 0, stream>>>(tpl, cp, q0, out, wt);
    flow_rest<<<BTS * NTPL / 4, 256, 0, stream>>>(p_hist, q_hist, out, wt);
}